// Round 19
// baseline (40.490 us; speedup 1.0000x reference)
//
#include <hip/hip_runtime.h>

#define N_PTS 20000
#define CIN   32
#define COUT  64
#define KK    4
#define KF    64
#define KDIM  2048          // KF*CIN
#define E_PAD 262144
#define EPS   1e-12f
#define FOUR_OVER_PI 1.27323954473516f
#define QB    8             // queries per block (fallback kernel)
#define MT32  32            // queries per block (fused kernel)

// prologue grid partition
#define NB_Q 1024           // build_qstart  (E_PAD/256)
#define NB_G 1024           // geom          (E_PAD/256)
#define NB_W 512            // reorder_w     (131072/256)
#define NB_F 1250           // feats bf16 pack (320000/256)
#define NB_D 313            // dense head MFMA (20000 queries / 64 per block)

typedef __attribute__((ext_vector_type(8))) short bf16x8;
typedef __attribute__((ext_vector_type(4))) float f32x4;

__device__ __forceinline__ float sgnf(float v) {
    return v > 0.f ? 1.f : (v < 0.f ? -1.f : 0.f);
}
__device__ __forceinline__ int imin(int a, int b) { return a < b ? a : b; }
__device__ __forceinline__ int imax(int a, int b) { return a > b ? a : b; }

__device__ __forceinline__ unsigned short f2bf(float f) {   // RNE f32->bf16
    unsigned u = __float_as_uint(f);
    u = u + 0x7fffu + ((u >> 16) & 1u);
    return (unsigned short)(u >> 16);
}

// HW packed conversion: lo16 = bf16(a), hi16 = bf16(b), RNE.
__device__ __forceinline__ unsigned cvtpk(float a, float b) {
    unsigned r;
    asm("v_cvt_pk_bf16_f32 %0, %1, %2" : "=v"(r) : "v"(a), "v"(b));
    return r;
}

// ball_to_cube_volume_preserving + trilinear cell (f32, op-for-op vs ref).
__device__ __forceinline__ void edge_geom(
    const float* __restrict__ pos, int n, int q,
    int& cellb, float& ofx, float& ofy, float& ofz)
{
    const float rx = (pos[n * 3 + 0] - pos[q * 3 + 0]) * 20.f;
    const float ry = (pos[n * 3 + 1] - pos[q * 3 + 1]) * 20.f;
    const float rz = (pos[n * 3 + 2] - pos[q * 3 + 2]) * 20.f;
    const float sq   = rx * rx + ry * ry + rz * rz;
    const float nrm  = sqrtf(fmaxf(sq, EPS));
    const float rxy2 = rx * rx + ry * ry;
    const bool  top  = (1.25f * rz * rz > rxy2);
    const float s_top  = sqrtf(fmaxf(3.f * nrm / (nrm + fabsf(rz) + EPS), EPS));
    const float s_side = nrm / sqrtf(fmaxf(rxy2, EPS));
    float cx = top ? rx * s_top : rx * s_side;
    float cy = top ? ry * s_top : ry * s_side;
    float cz = top ? sgnf(rz) * nrm : 1.5f * rz;
    if (sq < EPS) { cx = 0.f; cy = 0.f; cz = 0.f; }
    const float rc2 = cx * cx + cy * cy;
    const float rxy = sqrtf(fmaxf(rc2, EPS));
    const bool  xbig = fabsf(cy) <= fabsf(cx);
    const float safe_x = (fabsf(cx) > EPS) ? cx : 1.f;
    const float safe_y = (fabsf(cy) > EPS) ? cy : 1.f;
    const float qxv = sgnf(cx) * rxy;
    const float qyv = sgnf(cy) * rxy;
    float bx = xbig ? qxv : qyv * FOUR_OVER_PI * atanf(cx / safe_y);
    float by = xbig ? qxv * FOUR_OVER_PI * atanf(cy / safe_x) : qyv;
    if (rc2 < EPS) { bx = 0.f; by = 0.f; }
    const float ux = fminf(fmaxf((bx + 1.f) * 0.5f * 3.f, 0.f), 3.f);
    const float uy = fminf(fmaxf((by + 1.f) * 0.5f * 3.f, 0.f), 3.f);
    const float uz = fminf(fmaxf((cz + 1.f) * 0.5f * 3.f, 0.f), 3.f);
    const int ix = imin(imax((int)floorf(ux), 0), 2);
    const int iy = imin(imax((int)floorf(uy), 0), 2);
    const int iz = imin(imax((int)floorf(uz), 0), 2);
    cellb = (iz * KK + iy) * KK + ix;
    ofx = ux - (float)ix; ofy = uy - (float)iy; ofz = uz - (float)iz;
}

// One launch, five independent prologue tasks, partitioned by blockIdx.
__global__ __launch_bounds__(256) void prologue_kernel(
    const float* __restrict__ feats, const float* __restrict__ pos,
    const float* __restrict__ Wconv, const float* __restrict__ Wd,
    const float* __restrict__ bd,
    const int* __restrict__ eq, const int* __restrict__ en,
    const float* __restrict__ ev, int strideQ, int strideN,
    int* __restrict__ qstart, unsigned short* __restrict__ Wfrag,
    unsigned* __restrict__ fbp, float4* __restrict__ rec,
    float* __restrict__ out)
{
    const int bid = blockIdx.x;
    const int tid = threadIdx.x;
    if (bid < NB_Q) {
        // ---- CSR offsets from sorted edge_q (padding keyed to N_PTS) ----
        const int e = bid * 256 + tid;
        int k = (ev[e] > 0.f) ? eq[e * strideQ] : N_PTS;
        if (k > N_PTS) k = N_PTS;
        int kp = -1;
        if (e > 0) {
            kp = (ev[e - 1] > 0.f) ? eq[(e - 1) * strideQ] : N_PTS;
            if (kp > N_PTS) kp = N_PTS;
        }
        for (int q = kp + 1; q <= k; ++q) qstart[q] = e;
        if (e == E_PAD - 1)
            for (int q = k + 1; q <= N_PTS; ++q) qstart[q] = E_PAD;
    } else if (bid < NB_Q + NB_G) {
        // ---- per-edge geometry record (valid edges only) ----
        const int e = (bid - NB_Q) * 256 + tid;
        if (ev[e] > 0.f) {
            const int q = eq[e * strideQ];
            const int n = en[e * strideN];
            int ib; float fx, fy, fz;
            edge_geom(pos, n, q, ib, fx, fy, fz);
            float4 r;
            r.x = fx; r.y = fy; r.z = fz;
            r.w = __int_as_float(n | (ib << 16) | (1 << 22));
            rec[e] = r;
        }
    } else if (bid < NB_Q + NB_G + NB_W) {
        // ---- W -> bf16 B-fragment order: Wfrag[ks][nf][lane][j] ----
        const int idx = (bid - NB_Q - NB_G) * 256 + tid;
        const int j    = idx & 7;
        const int lane = (idx >> 3) & 63;
        const int nf   = (idx >> 9) & 3;
        const int ks   = idx >> 11;
        const int k    = ks * 32 + ((lane >> 4) << 3) + j;
        const int col  = nf * 16 + (lane & 15);
        Wfrag[idx] = f2bf(Wconv[k * COUT + col]);
    } else if (bid < NB_Q + NB_G + NB_W + NB_F) {
        // ---- feats f32 -> packed bf16 pairs: fbp[n*16+c] = (ch c, ch c+16)
        const int i = (bid - NB_Q - NB_G - NB_W) * 256 + tid;  // < 320000
        const int n = i >> 4, c = i & 15;
        fbp[i] = cvtpk(feats[n * CIN + c], feats[n * CIN + c + 16]);
    } else {
        // ---- dense head: out2 = feats @ Wd + bd, via MFMA ----
        const int db   = bid - NB_Q - NB_G - NB_W - NB_F;
        const int wv   = tid >> 6, lane = tid & 63;
        const int r16  = lane & 15, kgrp = lane >> 4;
        const int qb   = (db * 4 + wv) * 16;
        if (qb < N_PTS) {
            const float4 f0 = *(const float4*)(feats + (size_t)(qb + r16) * CIN + kgrp * 8);
            const float4 f1 = *(const float4*)(feats + (size_t)(qb + r16) * CIN + kgrp * 8 + 4);
            bf16x8 a8;
            ((unsigned*)&a8)[0] = cvtpk(f0.x, f0.y);
            ((unsigned*)&a8)[1] = cvtpk(f0.z, f0.w);
            ((unsigned*)&a8)[2] = cvtpk(f1.x, f1.y);
            ((unsigned*)&a8)[3] = cvtpk(f1.z, f1.w);
            #pragma unroll
            for (int nf = 0; nf < 4; ++nf) {
                bf16x8 b8;
                #pragma unroll
                for (int jp = 0; jp < 4; ++jp) {
                    const float w0 = Wd[(kgrp * 8 + jp * 2)     * COUT + nf * 16 + r16];
                    const float w1 = Wd[(kgrp * 8 + jp * 2 + 1) * COUT + nf * 16 + r16];
                    ((unsigned*)&b8)[jp] = cvtpk(w0, w1);
                }
                f32x4 acc = {0.f, 0.f, 0.f, 0.f};
                acc = __builtin_amdgcn_mfma_f32_16x16x32_bf16(a8, b8, acc, 0, 0, 0);
                const float bo = bd[nf * 16 + r16];
                #pragma unroll
                for (int rg = 0; rg < 4; ++rg) {
                    const int q = qb + kgrp * 4 + rg;
                    out[(size_t)N_PTS * COUT + q * COUT + nf * 16 + r16] = acc[rg] + bo;
                }
            }
        }
    }
}

// Fused MT32: 32 queries/block, 16 waves (1024 thr, launch_bounds(1024,4)
// -> 128 VGPR cap, body ~70: no spill). Phase A identical per-wave shape
// to the proven MT16 kernel (wave w owns {w, 31-w}, 4 waves/SIMD). Phase B
// halves per-query Wfrag L2 traffic: 625 blocks x 256 KB (W loaded once
// per (ks,nf), reused across both M-halves). partial[] aliased onto Zl
// after a barrier (Zl dead once A-frags consumed).
__global__ __launch_bounds__(1024, 4) void fused_kernel(
    const unsigned* __restrict__ fbp,
    const float4* __restrict__ rec,
    const unsigned short* __restrict__ Wfrag,
    const int* __restrict__ qstart, float* __restrict__ out)
{
    __shared__ __align__(16) unsigned short Zl[MT32 * KDIM];   // 128 KB
    __shared__ __align__(16) float4 ebuf[16][2][36];           // 18.4 KB

    const int t    = threadIdx.x;
    const int w    = t >> 6;            // 0..15
    const int lane = t & 63;
    const int r16  = lane & 15;
    const int kgrp = lane >> 4;
    const int q0   = blockIdx.x * MT32;

    // ---------- Phase A: pipelined MFMA scatter (2 queries/wave) --------
    const int dxc = r16 & 3, dyc = r16 >> 2;   // this lane's cell coords
    {
        const int qA  = w;
        const int qB  = 31 - w;
        const int lo0 = qstart[q0 + qA];
        const int hi0 = qstart[q0 + qA + 1];
        const int lo1 = qstart[q0 + qB];
        const int hi1 = qstart[q0 + qB + 1];
        const int nch0 = imax(1, (hi0 - lo0 + 31) >> 5);
        const int nch1 = imax(1, (hi1 - lo1 + 31) >> 5);
        const int NC   = nch0 + nch1;            // >= 2

        // initial stage: lanes<32 -> flat chunk 0, lanes>=32 -> flat chunk 1
        {
            const int sfi = lane >> 5, l32 = lane & 31;
            const int isq1 = sfi >= nch0;
            const int c    = isq1 ? sfi - nch0 : sfi;
            const int lo   = isq1 ? lo1 : lo0;
            const int hi   = isq1 ? hi1 : hi0;
            const int e    = lo + c * 32 + l32;
            float4 r;
            if (e < hi) r = rec[e];
            else { r.x = 0.f; r.y = 0.f; r.z = 0.f; r.w = __int_as_float(0); }
            ebuf[w][sfi][l32 + (l32 >> 3)] = r;   // padded index
        }

        f32x4 acc[2][4];
        #pragma unroll
        for (int mf = 0; mf < 2; ++mf)
            #pragma unroll
            for (int nf = 0; nf < 4; ++nf)
                acc[mf][nf] = (f32x4){0.f, 0.f, 0.f, 0.f};

        for (int fi = 0; fi < NC; ++fi) {
            // query-boundary: flush qA's Z row, restart accumulator
            if (fi == nch0) {
                const int qs = qA;
                #pragma unroll
                for (int mf = 0; mf < 2; ++mf)
                    #pragma unroll
                    for (int nf = 0; nf < 4; ++nf) {
                        uint2 dv;
                        dv.x = cvtpk(acc[mf][nf][0], acc[mf][nf][1]);
                        dv.y = cvtpk(acc[mf][nf][2], acc[mf][nf][3]);
                        const int g      = nf * 16 + r16;
                        const int slot   = g * 128 + qs * 4 + mf * 2 + (kgrp >> 1);
                        const int stored = slot ^ (g & 7);
                        *(uint2*)&Zl[stored * 8 + (kgrp & 1) * 4] = dv;
                        acc[mf][nf] = (f32x4){0.f, 0.f, 0.f, 0.f};
                    }
            }
            // compute chunk fi from ebuf[w][fi&1]
            const float4* buf = &ebuf[w][fi & 1][0];
            bf16x8 bP[4], af[2];
            #pragma unroll
            for (int jp = 0; jp < 4; ++jp) {
                float p[2][4];
                #pragma unroll
                for (int h = 0; h < 2; ++h) {
                    const int j = jp * 2 + h;
                    const float4 r = buf[kgrp * 9 + j];   // padded index
                    const int meta = __float_as_int(r.w);
                    const int n    = meta & 0xFFFF;
                    const int ib   = (meta >> 16) & 63;
                    const float valid = (meta & (1 << 22)) ? 1.f : 0.f;
                    const int ix = ib & 3, iy = (ib >> 2) & 3, iz = ib >> 4;
                    const float wx = (dxc == ix) ? (1.f - r.x)
                                   : ((dxc == ix + 1) ? r.x : 0.f);
                    const float wy = (dyc == iy) ? (1.f - r.y)
                                   : ((dyc == iy + 1) ? r.y : 0.f);
                    const float wxy = wx * wy * valid;
                    const float z0 = wxy * (1.f - r.z), z1 = wxy * r.z;
                    p[h][0] = (iz == 0) ? z0 : 0.f;
                    p[h][1] = (iz == 0) ? z1 : ((iz == 1) ? z0 : 0.f);
                    p[h][2] = (iz == 2) ? z0 : ((iz == 1) ? z1 : 0.f);
                    p[h][3] = (iz == 2) ? z1 : 0.f;
                    // packed gather: one 4B load = channels r16 and r16+16
                    const unsigned uf = fbp[(size_t)n * 16 + r16];
                    af[0][j] = (short)(uf & 0xFFFFu);
                    af[1][j] = (short)(uf >> 16);
                }
                #pragma unroll
                for (int nf = 0; nf < 4; ++nf)
                    ((unsigned*)&bP[nf])[jp] = cvtpk(p[0][nf], p[1][nf]);
            }
            #pragma unroll
            for (int nf = 0; nf < 4; ++nf) {
                acc[0][nf] = __builtin_amdgcn_mfma_f32_16x16x32_bf16(
                    af[0], bP[nf], acc[0][nf], 0, 0, 0);
                acc[1][nf] = __builtin_amdgcn_mfma_f32_16x16x32_bf16(
                    af[1], bP[nf], acc[1][nf], 0, 0, 0);
            }
            // stage chunk fi+2 into the buffer just consumed (lanes<32)
            const int nfi = fi + 2;
            if (nfi < NC && lane < 32) {
                const int isq1 = nfi >= nch0;
                const int c    = isq1 ? nfi - nch0 : nfi;
                const int lo   = isq1 ? lo1 : lo0;
                const int hi   = isq1 ? hi1 : hi0;
                const int e    = lo + c * 32 + lane;
                float4 r;
                if (e < hi) r = rec[e];
                else { r.x = 0.f; r.y = 0.f; r.z = 0.f;
                       r.w = __int_as_float(0); }
                ebuf[w][fi & 1][lane + (lane >> 3)] = r;   // padded index
            }
        }
        // flush qB's Z row
        {
            const int qs = qB;
            #pragma unroll
            for (int mf = 0; mf < 2; ++mf)
                #pragma unroll
                for (int nf = 0; nf < 4; ++nf) {
                    uint2 dv;
                    dv.x = cvtpk(acc[mf][nf][0], acc[mf][nf][1]);
                    dv.y = cvtpk(acc[mf][nf][2], acc[mf][nf][3]);
                    const int g      = nf * 16 + r16;
                    const int slot   = g * 128 + qs * 4 + mf * 2 + (kgrp >> 1);
                    const int stored = slot ^ (g & 7);
                    *(uint2*)&Zl[stored * 8 + (kgrp & 1) * 4] = dv;
                }
        }
    }
    __syncthreads();

    // ---------- Phase B: out = Zl x Wfrag ----------
    // wave = (kq, nfB): kq in 0..3 K-quarters (16 ks), nfB col-frag.
    // W-frag loaded once per (ks,nfB), reused for both M-halves.
    f32x4 accB[2];
    {
        const int kq  = w >> 2;
        const int nfB = w & 3;
        accB[0] = (f32x4){0.f, 0.f, 0.f, 0.f};
        accB[1] = (f32x4){0.f, 0.f, 0.f, 0.f};
        __builtin_amdgcn_s_setprio(1);
        #pragma unroll 4
        for (int i = 0; i < 16; ++i) {
            const int ks = kq * 16 + i;
            const bf16x8 b =
                *(const bf16x8*)(Wfrag + (((ks * 4 + nfB) * 64) + lane) * 8);
            const int st0 = (ks * 128 + r16 * 4 + kgrp) ^ (ks & 7);
            const int st1 = (ks * 128 + (16 + r16) * 4 + kgrp) ^ (ks & 7);
            const bf16x8 a0 = *(const bf16x8*)&Zl[st0 * 8];
            const bf16x8 a1 = *(const bf16x8*)&Zl[st1 * 8];
            accB[0] = __builtin_amdgcn_mfma_f32_16x16x32_bf16(a0, b, accB[0], 0, 0, 0);
            accB[1] = __builtin_amdgcn_mfma_f32_16x16x32_bf16(a1, b, accB[1], 0, 0, 0);
        }
        __builtin_amdgcn_s_setprio(0);
    }
    __syncthreads();   // all Zl reads done -> safe to alias partial onto Zl

    // ---------- partial write (aliased onto Zl) + epilogue ----------
    {
        float (*partial)[MT32][COUT] = (float (*)[MT32][COUT])Zl;  // 32 KB
        const int kq  = w >> 2;
        const int nfB = w & 3;
        #pragma unroll
        for (int mh = 0; mh < 2; ++mh)
            #pragma unroll
            for (int rg = 0; rg < 4; ++rg)
                partial[kq][mh * 16 + kgrp * 4 + rg][nfB * 16 + r16] =
                    accB[mh][rg];
        __syncthreads();
        #pragma unroll
        for (int rep = 0; rep < MT32 * COUT / 1024; ++rep) {
            const int idx = rep * 1024 + t;
            const int r = idx >> 6, o = idx & 63;
            out[(q0 + r) * COUT + o] = partial[0][r][o] + partial[1][r][o] +
                                       partial[2][r][o] + partial[3][r][o];
        }
    }
}

// ---------------- Fallback (round-2 monolithic) if ws too small ----------
__global__ __launch_bounds__(256) void conv_dense_kernel(
    const float* __restrict__ feats, const float* __restrict__ pos,
    const float* __restrict__ Wconv, const float* __restrict__ Wd,
    const float* __restrict__ bd,
    const int* __restrict__ en, const float* __restrict__ ev,
    const int* __restrict__ qstart, int strideN,
    float* __restrict__ out)
{
    __shared__ float Z[QB][KF][CIN];
    __shared__ float partial[4][QB][COUT];
    __shared__ int   rec_n[256], rec_b[256];
    __shared__ float rec_fx[256], rec_fy[256], rec_fz[256];
    __shared__ int   qs9[QB + 1];

    const int t = threadIdx.x, wave = t >> 6, lane = t & 63;
    const int q0 = blockIdx.x * QB;
    if (t <= QB) qs9[t] = qstart[q0 + t];
    float* zf = &Z[0][0][0];
    for (int j = t; j < QB * KF * CIN; j += 256) zf[j] = 0.f;
    __syncthreads();
    const int eLo = qs9[0], eHi = qs9[QB];
    const int ci = lane & 31, dbase = lane >> 5;
    for (int cb = eLo; cb < eHi; cb += 256) {
        const int cnt = imin(256, eHi - cb);
        if (t < cnt) {
            const int e = cb + t;
            int q = q0;
            #pragma unroll
            for (int s = 1; s < QB; ++s) if (e >= qs9[s]) q = q0 + s;
            int nn = ((const int*)en)[e];
            int ib; float fx, fy, fz;
            edge_geom(pos, nn, q, ib, fx, fy, fz);
            rec_n[t] = nn; rec_b[t] = ib;
            rec_fx[t] = fx; rec_fy[t] = fy; rec_fz[t] = fz;
        }
        __syncthreads();
        for (int s = 0; s < QB / 4; ++s) {
            const int qs = wave * (QB / 4) + s;
            const int lo = imax(qs9[qs], cb);
            const int hi = imin(qs9[qs + 1], cb + cnt);
            for (int e = lo; e < hi; ++e) {
                const int r = e - cb;
                const int n = rec_n[r], ib = rec_b[r];
                const float fx = rec_fx[r], fy = rec_fy[r], fz = rec_fz[r];
                const float fj = feats[n * CIN + ci];
                const float wxf = dbase ? fx : 1.f - fx;
                #pragma unroll
                for (int dd = 0; dd < 4; ++dd) {
                    const int dy = dd & 1, dz = dd >> 1;
                    const float wv = (dz ? fz : 1.f - fz) * (dy ? fy : 1.f - fy) * wxf;
                    Z[qs][ib + dz * 16 + dy * 4 + dbase][ci] += fj * wv;
                }
            }
        }
        __syncthreads();
    }
    float acc[QB];
    #pragma unroll
    for (int qs = 0; qs < QB; ++qs) acc[qs] = 0.f;
    const int o = lane;
    for (int kk = 0; kk < KF / 4; ++kk) {
        const int kf = wave * (KF / 4) + kk;
        #pragma unroll
        for (int ii = 0; ii < CIN; ii += 4) {
            float4 z4[QB];
            #pragma unroll
            for (int qs = 0; qs < QB; ++qs)
                z4[qs] = *(const float4*)&Z[qs][kf][ii];
            #pragma unroll
            for (int c = 0; c < 4; ++c) {
                const float wv = Wconv[(kf * CIN + ii + c) * COUT + o];
                #pragma unroll
                for (int qs = 0; qs < QB; ++qs)
                    acc[qs] += wv * ((const float*)&z4[qs])[c];
            }
        }
    }
    #pragma unroll
    for (int qs = 0; qs < QB; ++qs) partial[wave][qs][o] = acc[qs];
    __syncthreads();
    for (int s = 0; s < QB / 4; ++s) {
        const int qs = wave * (QB / 4) + s;
        const int q  = q0 + qs;
        out[q * COUT + o] = partial[0][qs][o] + partial[1][qs][o] +
                            partial[2][qs][o] + partial[3][qs][o];
        float dacc = bd[o];
        #pragma unroll
        for (int ii = 0; ii < CIN; ++ii)
            dacc += feats[q * CIN + ii] * Wd[ii * COUT + o];
        out[N_PTS * COUT + q * COUT + o] = dacc;
    }
}

// Repack en to int32 contiguous (fallback path only).
__global__ __launch_bounds__(256) void pack_en_kernel(
    const int* __restrict__ en, int stride, int* __restrict__ en32)
{
    const int e = blockIdx.x * 256 + threadIdx.x;
    if (e < E_PAD) en32[e] = en[e * stride];
}

// qstart-only builder for the fallback path.
__global__ __launch_bounds__(256) void build_qstart_kernel(
    const int* __restrict__ eq, const float* __restrict__ ev,
    int stride, int* __restrict__ qstart)
{
    int e = blockIdx.x * 256 + threadIdx.x;
    if (e >= E_PAD) return;
    int k = (ev[e] > 0.f) ? eq[e * stride] : N_PTS;
    if (k > N_PTS) k = N_PTS;
    int kp = -1;
    if (e > 0) {
        kp = (ev[e - 1] > 0.f) ? eq[(e - 1) * stride] : N_PTS;
        if (kp > N_PTS) kp = N_PTS;
    }
    for (int q = kp + 1; q <= k; ++q) qstart[q] = e;
    if (e == E_PAD - 1) {
        for (int q = k + 1; q <= N_PTS; ++q) qstart[q] = E_PAD;
    }
}

extern "C" void kernel_launch(void* const* d_in, const int* in_sizes, int n_in,
                              void* d_out, int out_size, void* d_ws, size_t ws_size,
                              hipStream_t stream)
{
    const float* feats = (const float*)d_in[0];
    const float* pos   = (const float*)d_in[1];
    const float* Wconv = (const float*)d_in[2];
    const float* Wd    = (const float*)d_in[3];
    const float* bd    = (const float*)d_in[4];
    const int*   eq    = (const int*)d_in[5];
    const int*   en    = (const int*)d_in[6];
    const float* ev    = (const float*)d_in[7];
    const int strideQ = in_sizes[5] / E_PAD;   // int32 vs int64 hedge
    const int strideN = in_sizes[6] / E_PAD;

    int* qstart = (int*)d_ws;
    const size_t offW  = 81920;                       // Wfrag   (256 KB)
    const size_t offFB = offW + 262144;               // fbp     (1.28 MB)
    const size_t offR  = offFB + (size_t)N_PTS * CIN * 2;  // rec (4 MB)
    const size_t needed = offR + (size_t)E_PAD * 16;

    if (ws_size >= needed) {
        unsigned short* Wfrag = (unsigned short*)((char*)d_ws + offW);
        unsigned*       fbp   = (unsigned*)((char*)d_ws + offFB);
        float4*         rec   = (float4*)((char*)d_ws + offR);
        prologue_kernel<<<NB_Q + NB_G + NB_W + NB_F + NB_D, 256, 0, stream>>>(
            feats, pos, Wconv, Wd, bd, eq, en, ev, strideQ, strideN,
            qstart, Wfrag, fbp, rec, (float*)d_out);
        fused_kernel<<<N_PTS / MT32, 1024, 0, stream>>>(
            fbp, rec, Wfrag, qstart, (float*)d_out);
    } else {
        build_qstart_kernel<<<E_PAD / 256, 256, 0, stream>>>(
            eq, ev, strideQ, qstart);
        int* en32 = (int*)((char*)d_ws + offW);
        pack_en_kernel<<<E_PAD / 256, 256, 0, stream>>>(en, strideN, en32);
        conv_dense_kernel<<<N_PTS / QB, 256, 0, stream>>>(
            feats, pos, Wconv, Wd, bd, en32, ev, qstart, 1, (float*)d_out);
    }
}

// Round 20
// 34.663 us; speedup vs baseline: 1.1681x; 1.1681x over previous
//
#include <hip/hip_runtime.h>

#define N_PTS 20000
#define CIN   32
#define COUT  64
#define KK    4
#define KF    64
#define KDIM  2048          // KF*CIN
#define E_PAD 262144
#define EPS   1e-12f
#define FOUR_OVER_PI 1.27323954473516f
#define QB    8             // queries per block (fallback kernel)
#define MT16  16            // queries per block (fused kernel)

// prologue grid partition
#define NB_Q 1024           // build_qstart  (E_PAD/256)
#define NB_G 1024           // geom          (E_PAD/256)
#define NB_W 512            // reorder_w     (131072/256)
#define NB_F 1250           // feats bf16 pack (320000/256)
#define NB_D 313            // dense head MFMA (20000 queries / 64 per block)

typedef __attribute__((ext_vector_type(8))) short bf16x8;
typedef __attribute__((ext_vector_type(4))) float f32x4;

__device__ __forceinline__ float sgnf(float v) {
    return v > 0.f ? 1.f : (v < 0.f ? -1.f : 0.f);
}
__device__ __forceinline__ int imin(int a, int b) { return a < b ? a : b; }
__device__ __forceinline__ int imax(int a, int b) { return a > b ? a : b; }

__device__ __forceinline__ unsigned short f2bf(float f) {   // RNE f32->bf16
    unsigned u = __float_as_uint(f);
    u = u + 0x7fffu + ((u >> 16) & 1u);
    return (unsigned short)(u >> 16);
}

// HW packed conversion: lo16 = bf16(a), hi16 = bf16(b), RNE.
__device__ __forceinline__ unsigned cvtpk(float a, float b) {
    unsigned r;
    asm("v_cvt_pk_bf16_f32 %0, %1, %2" : "=v"(r) : "v"(a), "v"(b));
    return r;
}

// ball_to_cube_volume_preserving + trilinear cell (f32, op-for-op vs ref).
__device__ __forceinline__ void edge_geom(
    const float* __restrict__ pos, int n, int q,
    int& cellb, float& ofx, float& ofy, float& ofz)
{
    const float rx = (pos[n * 3 + 0] - pos[q * 3 + 0]) * 20.f;
    const float ry = (pos[n * 3 + 1] - pos[q * 3 + 1]) * 20.f;
    const float rz = (pos[n * 3 + 2] - pos[q * 3 + 2]) * 20.f;
    const float sq   = rx * rx + ry * ry + rz * rz;
    const float nrm  = sqrtf(fmaxf(sq, EPS));
    const float rxy2 = rx * rx + ry * ry;
    const bool  top  = (1.25f * rz * rz > rxy2);
    const float s_top  = sqrtf(fmaxf(3.f * nrm / (nrm + fabsf(rz) + EPS), EPS));
    const float s_side = nrm / sqrtf(fmaxf(rxy2, EPS));
    float cx = top ? rx * s_top : rx * s_side;
    float cy = top ? ry * s_top : ry * s_side;
    float cz = top ? sgnf(rz) * nrm : 1.5f * rz;
    if (sq < EPS) { cx = 0.f; cy = 0.f; cz = 0.f; }
    const float rc2 = cx * cx + cy * cy;
    const float rxy = sqrtf(fmaxf(rc2, EPS));
    const bool  xbig = fabsf(cy) <= fabsf(cx);
    const float safe_x = (fabsf(cx) > EPS) ? cx : 1.f;
    const float safe_y = (fabsf(cy) > EPS) ? cy : 1.f;
    const float qxv = sgnf(cx) * rxy;
    const float qyv = sgnf(cy) * rxy;
    float bx = xbig ? qxv : qyv * FOUR_OVER_PI * atanf(cx / safe_y);
    float by = xbig ? qxv * FOUR_OVER_PI * atanf(cy / safe_x) : qyv;
    if (rc2 < EPS) { bx = 0.f; by = 0.f; }
    const float ux = fminf(fmaxf((bx + 1.f) * 0.5f * 3.f, 0.f), 3.f);
    const float uy = fminf(fmaxf((by + 1.f) * 0.5f * 3.f, 0.f), 3.f);
    const float uz = fminf(fmaxf((cz + 1.f) * 0.5f * 3.f, 0.f), 3.f);
    const int ix = imin(imax((int)floorf(ux), 0), 2);
    const int iy = imin(imax((int)floorf(uy), 0), 2);
    const int iz = imin(imax((int)floorf(uz), 0), 2);
    cellb = (iz * KK + iy) * KK + ix;
    ofx = ux - (float)ix; ofy = uy - (float)iy; ofz = uz - (float)iz;
}

// One launch, five independent prologue tasks, partitioned by blockIdx.
__global__ __launch_bounds__(256) void prologue_kernel(
    const float* __restrict__ feats, const float* __restrict__ pos,
    const float* __restrict__ Wconv, const float* __restrict__ Wd,
    const float* __restrict__ bd,
    const int* __restrict__ eq, const int* __restrict__ en,
    const float* __restrict__ ev, int strideQ, int strideN,
    int* __restrict__ qstart, unsigned short* __restrict__ Wfrag,
    unsigned* __restrict__ fbp, float4* __restrict__ rec,
    float* __restrict__ out)
{
    const int bid = blockIdx.x;
    const int tid = threadIdx.x;
    if (bid < NB_Q) {
        // ---- CSR offsets from sorted edge_q (padding keyed to N_PTS) ----
        const int e = bid * 256 + tid;
        int k = (ev[e] > 0.f) ? eq[e * strideQ] : N_PTS;
        if (k > N_PTS) k = N_PTS;
        int kp = -1;
        if (e > 0) {
            kp = (ev[e - 1] > 0.f) ? eq[(e - 1) * strideQ] : N_PTS;
            if (kp > N_PTS) kp = N_PTS;
        }
        for (int q = kp + 1; q <= k; ++q) qstart[q] = e;
        if (e == E_PAD - 1)
            for (int q = k + 1; q <= N_PTS; ++q) qstart[q] = E_PAD;
    } else if (bid < NB_Q + NB_G) {
        // ---- per-edge geometry record (valid edges only) ----
        const int e = (bid - NB_Q) * 256 + tid;
        if (ev[e] > 0.f) {
            const int q = eq[e * strideQ];
            const int n = en[e * strideN];
            int ib; float fx, fy, fz;
            edge_geom(pos, n, q, ib, fx, fy, fz);
            float4 r;
            r.x = fx; r.y = fy; r.z = fz;
            r.w = __int_as_float(n | (ib << 16) | (1 << 22));
            rec[e] = r;
        }
    } else if (bid < NB_Q + NB_G + NB_W) {
        // ---- W -> bf16 B-fragment order: Wfrag[ks][nf][lane][j] ----
        const int idx = (bid - NB_Q - NB_G) * 256 + tid;
        const int j    = idx & 7;
        const int lane = (idx >> 3) & 63;
        const int nf   = (idx >> 9) & 3;
        const int ks   = idx >> 11;
        const int k    = ks * 32 + ((lane >> 4) << 3) + j;
        const int col  = nf * 16 + (lane & 15);
        Wfrag[idx] = f2bf(Wconv[k * COUT + col]);
    } else if (bid < NB_Q + NB_G + NB_W + NB_F) {
        // ---- feats f32 -> packed bf16 pairs: fbp[n*16+c] = (ch c, ch c+16)
        const int i = (bid - NB_Q - NB_G - NB_W) * 256 + tid;  // < 320000
        const int n = i >> 4, c = i & 15;
        fbp[i] = cvtpk(feats[n * CIN + c], feats[n * CIN + c + 16]);
    } else {
        // ---- dense head: out2 = feats @ Wd + bd, via MFMA ----
        const int db   = bid - NB_Q - NB_G - NB_W - NB_F;
        const int wv   = tid >> 6, lane = tid & 63;
        const int r16  = lane & 15, kgrp = lane >> 4;
        const int qb   = (db * 4 + wv) * 16;
        if (qb < N_PTS) {
            const float4 f0 = *(const float4*)(feats + (size_t)(qb + r16) * CIN + kgrp * 8);
            const float4 f1 = *(const float4*)(feats + (size_t)(qb + r16) * CIN + kgrp * 8 + 4);
            bf16x8 a8;
            ((unsigned*)&a8)[0] = cvtpk(f0.x, f0.y);
            ((unsigned*)&a8)[1] = cvtpk(f0.z, f0.w);
            ((unsigned*)&a8)[2] = cvtpk(f1.x, f1.y);
            ((unsigned*)&a8)[3] = cvtpk(f1.z, f1.w);
            #pragma unroll
            for (int nf = 0; nf < 4; ++nf) {
                bf16x8 b8;
                #pragma unroll
                for (int jp = 0; jp < 4; ++jp) {
                    const float w0 = Wd[(kgrp * 8 + jp * 2)     * COUT + nf * 16 + r16];
                    const float w1 = Wd[(kgrp * 8 + jp * 2 + 1) * COUT + nf * 16 + r16];
                    ((unsigned*)&b8)[jp] = cvtpk(w0, w1);
                }
                f32x4 acc = {0.f, 0.f, 0.f, 0.f};
                acc = __builtin_amdgcn_mfma_f32_16x16x32_bf16(a8, b8, acc, 0, 0, 0);
                const float bo = bd[nf * 16 + r16];
                #pragma unroll
                for (int rg = 0; rg < 4; ++rg) {
                    const int q = qb + kgrp * 4 + rg;
                    out[(size_t)N_PTS * COUT + q * COUT + nf * 16 + r16] = acc[rg] + bo;
                }
            }
        }
    }
}

// Fused (MT16, (512,4) — the proven 36.8 shell). NEW phase A: wave w owns
// ADJACENT queries {2w, 2w+1}, whose edges are CONTIGUOUS in rec; ONE
// masked chunk stream covers both (belongsA bit set at staging routes each
// edge's weight into bP_A or bP_B; dual accumulators; flush both at end).
// Typical pair = 21 edges -> 1 chunk instead of 2: decode/stage/gather halve.
__global__ __launch_bounds__(512, 4) void fused_kernel(
    const unsigned* __restrict__ fbp,
    const float4* __restrict__ rec,
    const unsigned short* __restrict__ Wfrag,
    const int* __restrict__ qstart, float* __restrict__ out)
{
    __shared__ __align__(16) unsigned short Zl[MT16 * KDIM];   // 64 KB
    __shared__ __align__(16) char scratch[9216];               // 9 KB union
    float4 (*ebuf)[2][36]   = (float4 (*)[2][36])scratch;          // phase A
    float  (*partial)[MT16][COUT] = (float (*)[MT16][COUT])scratch; // phase B+

    const int t    = threadIdx.x;
    const int w    = t >> 6;
    const int lane = t & 63;
    const int r16  = lane & 15;
    const int kgrp = lane >> 4;
    const int q0   = blockIdx.x * MT16;

    // ---------- Phase A: one masked chunk stream for 2 queries ----------
    const int dxc = r16 & 3, dyc = r16 >> 2;   // this lane's cell coords
    {
        const int lo  = qstart[q0 + 2 * w];
        const int mid = qstart[q0 + 2 * w + 1];
        const int hi  = qstart[q0 + 2 * w + 2];
        const int NC  = imax(1, (hi - lo + 31) >> 5);

        // initial stage: lanes<32 -> chunk 0, lanes>=32 -> chunk 1
        {
            const int sfi = lane >> 5, l32 = lane & 31;
            const int e   = lo + sfi * 32 + l32;
            float4 r;
            if (e < hi) r = rec[e];
            else { r.x = 0.f; r.y = 0.f; r.z = 0.f; r.w = __int_as_float(0); }
            int meta = __float_as_int(r.w);
            if (e < mid) meta |= (1 << 23);      // belongsA
            r.w = __int_as_float(meta);
            ebuf[w][sfi][l32 + (l32 >> 3)] = r;  // padded index
        }

        f32x4 accA[2][4], accB[2][4];
        #pragma unroll
        for (int mf = 0; mf < 2; ++mf)
            #pragma unroll
            for (int nf = 0; nf < 4; ++nf) {
                accA[mf][nf] = (f32x4){0.f, 0.f, 0.f, 0.f};
                accB[mf][nf] = (f32x4){0.f, 0.f, 0.f, 0.f};
            }

        for (int fi = 0; fi < NC; ++fi) {
            const float4* buf = &ebuf[w][fi & 1][0];
            bf16x8 bPA[4], bPB[4], af[2];
            #pragma unroll
            for (int jp = 0; jp < 4; ++jp) {
                float pA[2][4], pB[2][4];
                #pragma unroll
                for (int h = 0; h < 2; ++h) {
                    const int j = jp * 2 + h;
                    const float4 r = buf[kgrp * 9 + j];   // padded index
                    const int meta = __float_as_int(r.w);
                    const int n    = meta & 0xFFFF;
                    const int ib   = (meta >> 16) & 63;
                    const float valid = (meta & (1 << 22)) ? 1.f : 0.f;
                    const float selA  = (meta & (1 << 23)) ? 1.f : 0.f;
                    const int ix = ib & 3, iy = (ib >> 2) & 3, iz = ib >> 4;
                    const float wx = (dxc == ix) ? (1.f - r.x)
                                   : ((dxc == ix + 1) ? r.x : 0.f);
                    const float wy = (dyc == iy) ? (1.f - r.y)
                                   : ((dyc == iy + 1) ? r.y : 0.f);
                    const float wxy = wx * wy * valid;
                    const float z0 = wxy * (1.f - r.z), z1 = wxy * r.z;
                    float p0 = (iz == 0) ? z0 : 0.f;
                    float p1 = (iz == 0) ? z1 : ((iz == 1) ? z0 : 0.f);
                    float p2 = (iz == 2) ? z0 : ((iz == 1) ? z1 : 0.f);
                    float p3 = (iz == 2) ? z1 : 0.f;
                    pA[h][0] = p0 * selA;  pB[h][0] = p0 - pA[h][0];
                    pA[h][1] = p1 * selA;  pB[h][1] = p1 - pA[h][1];
                    pA[h][2] = p2 * selA;  pB[h][2] = p2 - pA[h][2];
                    pA[h][3] = p3 * selA;  pB[h][3] = p3 - pA[h][3];
                    // packed gather: one 4B load = channels r16 and r16+16
                    const unsigned uf = fbp[(size_t)n * 16 + r16];
                    af[0][j] = (short)(uf & 0xFFFFu);
                    af[1][j] = (short)(uf >> 16);
                }
                #pragma unroll
                for (int nf = 0; nf < 4; ++nf) {
                    ((unsigned*)&bPA[nf])[jp] = cvtpk(pA[0][nf], pA[1][nf]);
                    ((unsigned*)&bPB[nf])[jp] = cvtpk(pB[0][nf], pB[1][nf]);
                }
            }
            #pragma unroll
            for (int nf = 0; nf < 4; ++nf) {
                accA[0][nf] = __builtin_amdgcn_mfma_f32_16x16x32_bf16(
                    af[0], bPA[nf], accA[0][nf], 0, 0, 0);
                accA[1][nf] = __builtin_amdgcn_mfma_f32_16x16x32_bf16(
                    af[1], bPA[nf], accA[1][nf], 0, 0, 0);
                accB[0][nf] = __builtin_amdgcn_mfma_f32_16x16x32_bf16(
                    af[0], bPB[nf], accB[0][nf], 0, 0, 0);
                accB[1][nf] = __builtin_amdgcn_mfma_f32_16x16x32_bf16(
                    af[1], bPB[nf], accB[1][nf], 0, 0, 0);
            }
            // stage chunk fi+2 into the buffer just consumed (lanes<32)
            const int nfi = fi + 2;
            if (nfi < NC && lane < 32) {
                const int e = lo + nfi * 32 + lane;
                float4 r;
                if (e < hi) r = rec[e];
                else { r.x = 0.f; r.y = 0.f; r.z = 0.f;
                       r.w = __int_as_float(0); }
                int meta = __float_as_int(r.w);
                if (e < mid) meta |= (1 << 23);
                r.w = __int_as_float(meta);
                ebuf[w][fi & 1][lane + (lane >> 3)] = r;
            }
        }
        // flush both queries' Z rows (qsA = 2w, qsB = 2w+1)
        #pragma unroll
        for (int half = 0; half < 2; ++half) {
            const int qs = 2 * w + half;
            #pragma unroll
            for (int mf = 0; mf < 2; ++mf)
                #pragma unroll
                for (int nf = 0; nf < 4; ++nf) {
                    const f32x4 a = half ? accB[mf][nf] : accA[mf][nf];
                    uint2 dv;
                    dv.x = cvtpk(a[0], a[1]);
                    dv.y = cvtpk(a[2], a[3]);
                    const int g      = nf * 16 + r16;
                    const int slot   = g * 64 + qs * 4 + mf * 2 + (kgrp >> 1);
                    const int stored = slot ^ (g & 7);
                    *(uint2*)&Zl[stored * 8 + (kgrp & 1) * 4] = dv;
                }
        }
    }
    __syncthreads();

    // ---------- Phase B: out = Zl x Wfrag (dual accumulator) ----------
    {
        const int kw  = w >> 2;      // K-half
        const int nfB = w & 3;       // col-frag
        f32x4 acc0 = {0.f, 0.f, 0.f, 0.f};
        f32x4 acc1 = {0.f, 0.f, 0.f, 0.f};
        __builtin_amdgcn_s_setprio(1);
        #pragma unroll 4
        for (int i = 0; i < 16; ++i) {
            const int ksA = kw * 32 + 2 * i;
            const int ksB = ksA + 1;
            const int stA = (ksA * 64 + r16 * 4 + kgrp) ^ (ksA & 7);
            const int stB = (ksB * 64 + r16 * 4 + kgrp) ^ (ksB & 7);
            const bf16x8 aA = *(const bf16x8*)&Zl[stA * 8];
            const bf16x8 aB = *(const bf16x8*)&Zl[stB * 8];
            const bf16x8 bA =
                *(const bf16x8*)(Wfrag + (((ksA * 4 + nfB) * 64) + lane) * 8);
            const bf16x8 bB =
                *(const bf16x8*)(Wfrag + (((ksB * 4 + nfB) * 64) + lane) * 8);
            acc0 = __builtin_amdgcn_mfma_f32_16x16x32_bf16(aA, bA, acc0, 0, 0, 0);
            acc1 = __builtin_amdgcn_mfma_f32_16x16x32_bf16(aB, bB, acc1, 0, 0, 0);
        }
        __builtin_amdgcn_s_setprio(0);
        const f32x4 accB = acc0 + acc1;
        #pragma unroll
        for (int rg = 0; rg < 4; ++rg)
            partial[kw][kgrp * 4 + rg][nfB * 16 + r16] = accB[rg];
    }
    __syncthreads();

    // ---------- Epilogue: reduce K-halves (conv output only) ----------
    #pragma unroll
    for (int rep = 0; rep < MT16 * COUT / 512; ++rep) {
        const int idx = rep * 512 + t;
        const int r = idx >> 6, o = idx & 63;
        out[(q0 + r) * COUT + o] = partial[0][r][o] + partial[1][r][o];
    }
}

// ---------------- Fallback (round-2 monolithic) if ws too small ----------
__global__ __launch_bounds__(256) void conv_dense_kernel(
    const float* __restrict__ feats, const float* __restrict__ pos,
    const float* __restrict__ Wconv, const float* __restrict__ Wd,
    const float* __restrict__ bd,
    const int* __restrict__ en, const float* __restrict__ ev,
    const int* __restrict__ qstart, int strideN,
    float* __restrict__ out)
{
    __shared__ float Z[QB][KF][CIN];
    __shared__ float partial[4][QB][COUT];
    __shared__ int   rec_n[256], rec_b[256];
    __shared__ float rec_fx[256], rec_fy[256], rec_fz[256];
    __shared__ int   qs9[QB + 1];

    const int t = threadIdx.x, wave = t >> 6, lane = t & 63;
    const int q0 = blockIdx.x * QB;
    if (t <= QB) qs9[t] = qstart[q0 + t];
    float* zf = &Z[0][0][0];
    for (int j = t; j < QB * KF * CIN; j += 256) zf[j] = 0.f;
    __syncthreads();
    const int eLo = qs9[0], eHi = qs9[QB];
    const int ci = lane & 31, dbase = lane >> 5;
    for (int cb = eLo; cb < eHi; cb += 256) {
        const int cnt = imin(256, eHi - cb);
        if (t < cnt) {
            const int e = cb + t;
            int q = q0;
            #pragma unroll
            for (int s = 1; s < QB; ++s) if (e >= qs9[s]) q = q0 + s;
            int nn = ((const int*)en)[e];
            int ib; float fx, fy, fz;
            edge_geom(pos, nn, q, ib, fx, fy, fz);
            rec_n[t] = nn; rec_b[t] = ib;
            rec_fx[t] = fx; rec_fy[t] = fy; rec_fz[t] = fz;
        }
        __syncthreads();
        for (int s = 0; s < QB / 4; ++s) {
            const int qs = wave * (QB / 4) + s;
            const int lo = imax(qs9[qs], cb);
            const int hi = imin(qs9[qs + 1], cb + cnt);
            for (int e = lo; e < hi; ++e) {
                const int r = e - cb;
                const int n = rec_n[r], ib = rec_b[r];
                const float fx = rec_fx[r], fy = rec_fy[r], fz = rec_fz[r];
                const float fj = feats[n * CIN + ci];
                const float wxf = dbase ? fx : 1.f - fx;
                #pragma unroll
                for (int dd = 0; dd < 4; ++dd) {
                    const int dy = dd & 1, dz = dd >> 1;
                    const float wv = (dz ? fz : 1.f - fz) * (dy ? fy : 1.f - fy) * wxf;
                    Z[qs][ib + dz * 16 + dy * 4 + dbase][ci] += fj * wv;
                }
            }
        }
        __syncthreads();
    }
    float acc[QB];
    #pragma unroll
    for (int qs = 0; qs < QB; ++qs) acc[qs] = 0.f;
    const int o = lane;
    for (int kk = 0; kk < KF / 4; ++kk) {
        const int kf = wave * (KF / 4) + kk;
        #pragma unroll
        for (int ii = 0; ii < CIN; ii += 4) {
            float4 z4[QB];
            #pragma unroll
            for (int qs = 0; qs < QB; ++qs)
                z4[qs] = *(const float4*)&Z[qs][kf][ii];
            #pragma unroll
            for (int c = 0; c < 4; ++c) {
                const float wv = Wconv[(kf * CIN + ii + c) * COUT + o];
                #pragma unroll
                for (int qs = 0; qs < QB; ++qs)
                    acc[qs] += wv * ((const float*)&z4[qs])[c];
            }
        }
    }
    #pragma unroll
    for (int qs = 0; qs < QB; ++qs) partial[wave][qs][o] = acc[qs];
    __syncthreads();
    for (int s = 0; s < QB / 4; ++s) {
        const int qs = wave * (QB / 4) + s;
        const int q  = q0 + qs;
        out[q * COUT + o] = partial[0][qs][o] + partial[1][qs][o] +
                            partial[2][qs][o] + partial[3][qs][o];
        float dacc = bd[o];
        #pragma unroll
        for (int ii = 0; ii < CIN; ++ii)
            dacc += feats[q * CIN + ii] * Wd[ii * COUT + o];
        out[N_PTS * COUT + q * COUT + o] = dacc;
    }
}

// Repack en to int32 contiguous (fallback path only).
__global__ __launch_bounds__(256) void pack_en_kernel(
    const int* __restrict__ en, int stride, int* __restrict__ en32)
{
    const int e = blockIdx.x * 256 + threadIdx.x;
    if (e < E_PAD) en32[e] = en[e * stride];
}

// qstart-only builder for the fallback path.
__global__ __launch_bounds__(256) void build_qstart_kernel(
    const int* __restrict__ eq, const float* __restrict__ ev,
    int stride, int* __restrict__ qstart)
{
    int e = blockIdx.x * 256 + threadIdx.x;
    if (e >= E_PAD) return;
    int k = (ev[e] > 0.f) ? eq[e * stride] : N_PTS;
    if (k > N_PTS) k = N_PTS;
    int kp = -1;
    if (e > 0) {
        kp = (ev[e - 1] > 0.f) ? eq[(e - 1) * stride] : N_PTS;
        if (kp > N_PTS) kp = N_PTS;
    }
    for (int q = kp + 1; q <= k; ++q) qstart[q] = e;
    if (e == E_PAD - 1) {
        for (int q = k + 1; q <= N_PTS; ++q) qstart[q] = E_PAD;
    }
}

extern "C" void kernel_launch(void* const* d_in, const int* in_sizes, int n_in,
                              void* d_out, int out_size, void* d_ws, size_t ws_size,
                              hipStream_t stream)
{
    const float* feats = (const float*)d_in[0];
    const float* pos   = (const float*)d_in[1];
    const float* Wconv = (const float*)d_in[2];
    const float* Wd    = (const float*)d_in[3];
    const float* bd    = (const float*)d_in[4];
    const int*   eq    = (const int*)d_in[5];
    const int*   en    = (const int*)d_in[6];
    const float* ev    = (const float*)d_in[7];
    const int strideQ = in_sizes[5] / E_PAD;   // int32 vs int64 hedge
    const int strideN = in_sizes[6] / E_PAD;

    int* qstart = (int*)d_ws;
    const size_t offW  = 81920;                       // Wfrag   (256 KB)
    const size_t offFB = offW + 262144;               // fbp     (1.28 MB)
    const size_t offR  = offFB + (size_t)N_PTS * CIN * 2;  // rec (4 MB)
    const size_t needed = offR + (size_t)E_PAD * 16;

    if (ws_size >= needed) {
        unsigned short* Wfrag = (unsigned short*)((char*)d_ws + offW);
        unsigned*       fbp   = (unsigned*)((char*)d_ws + offFB);
        float4*         rec   = (float4*)((char*)d_ws + offR);
        prologue_kernel<<<NB_Q + NB_G + NB_W + NB_F + NB_D, 256, 0, stream>>>(
            feats, pos, Wconv, Wd, bd, eq, en, ev, strideQ, strideN,
            qstart, Wfrag, fbp, rec, (float*)d_out);
        fused_kernel<<<N_PTS / MT16, 512, 0, stream>>>(
            fbp, rec, Wfrag, qstart, (float*)d_out);
    } else {
        build_qstart_kernel<<<E_PAD / 256, 256, 0, stream>>>(
            eq, ev, strideQ, qstart);
        int* en32 = (int*)((char*)d_ws + offW);
        pack_en_kernel<<<E_PAD / 256, 256, 0, stream>>>(en, strideN, en32);
        conv_dense_kernel<<<N_PTS / QB, 256, 0, stream>>>(
            feats, pos, Wconv, Wd, bd, en32, ev, qstart, 1, (float*)d_out);
    }
}

// Round 21
// 34.495 us; speedup vs baseline: 1.1738x; 1.0049x over previous
//
#include <hip/hip_runtime.h>

#define N_PTS 20000
#define CIN   32
#define COUT  64
#define KK    4
#define KF    64
#define KDIM  2048          // KF*CIN
#define E_PAD 262144
#define EPS   1e-12f
#define FOUR_OVER_PI 1.27323954473516f
#define QB    8             // queries per block (fallback kernel)
#define MT16  16            // queries per block (fused kernel)

// prologue grid partition (geom FIRST: heaviest blocks dispatch earliest)
#define NB_G 1024           // geom          (E_PAD/256)
#define NB_Q 1024           // build_qstart  (E_PAD/256)
#define NB_W 512            // reorder_w     (131072/256)
#define NB_F 1250           // feats bf16 pack (320000/256)
#define NB_D 313            // dense head MFMA (20000 queries / 64 per block)

typedef __attribute__((ext_vector_type(8))) short bf16x8;
typedef __attribute__((ext_vector_type(4))) float f32x4;

__device__ __forceinline__ float sgnf(float v) {
    return v > 0.f ? 1.f : (v < 0.f ? -1.f : 0.f);
}
__device__ __forceinline__ int imin(int a, int b) { return a < b ? a : b; }
__device__ __forceinline__ int imax(int a, int b) { return a > b ? a : b; }

__device__ __forceinline__ unsigned short f2bf(float f) {   // RNE f32->bf16
    unsigned u = __float_as_uint(f);
    u = u + 0x7fffu + ((u >> 16) & 1u);
    return (unsigned short)(u >> 16);
}

// HW packed conversion: lo16 = bf16(a), hi16 = bf16(b), RNE.
__device__ __forceinline__ unsigned cvtpk(float a, float b) {
    unsigned r;
    asm("v_cvt_pk_bf16_f32 %0, %1, %2" : "=v"(r) : "v"(a), "v"(b));
    return r;
}

// Minimax odd polynomial for atan(x), |x| <= 1 (guaranteed here: the
// argument is always min/max of two magnitudes). Max err ~1e-5 rad ->
// weight error ~2e-5, negligible vs the 5.8e-2 threshold. Replaces the
// ~40-instr libm atanf in the hot geom pass.
__device__ __forceinline__ float atan_poly(float x) {
    const float x2 = x * x;
    float r = -0.0117212f;
    r = fmaf(r, x2,  0.05265332f);
    r = fmaf(r, x2, -0.11643287f);
    r = fmaf(r, x2,  0.19354346f);
    r = fmaf(r, x2, -0.33262347f);
    r = fmaf(r, x2,  0.99997726f);
    return x * r;
}

// ball_to_cube_volume_preserving + trilinear cell (f32; atan via poly).
__device__ __forceinline__ void edge_geom(
    const float* __restrict__ pos, int n, int q,
    int& cellb, float& ofx, float& ofy, float& ofz)
{
    const float rx = (pos[n * 3 + 0] - pos[q * 3 + 0]) * 20.f;
    const float ry = (pos[n * 3 + 1] - pos[q * 3 + 1]) * 20.f;
    const float rz = (pos[n * 3 + 2] - pos[q * 3 + 2]) * 20.f;
    const float sq   = rx * rx + ry * ry + rz * rz;
    const float nrm  = sqrtf(fmaxf(sq, EPS));
    const float rxy2 = rx * rx + ry * ry;
    const bool  top  = (1.25f * rz * rz > rxy2);
    const float s_top  = sqrtf(fmaxf(3.f * nrm / (nrm + fabsf(rz) + EPS), EPS));
    const float s_side = nrm / sqrtf(fmaxf(rxy2, EPS));
    float cx = top ? rx * s_top : rx * s_side;
    float cy = top ? ry * s_top : ry * s_side;
    float cz = top ? sgnf(rz) * nrm : 1.5f * rz;
    if (sq < EPS) { cx = 0.f; cy = 0.f; cz = 0.f; }
    const float rc2 = cx * cx + cy * cy;
    const float rxy = sqrtf(fmaxf(rc2, EPS));
    const bool  xbig = fabsf(cy) <= fabsf(cx);
    const float safe_x = (fabsf(cx) > EPS) ? cx : 1.f;
    const float safe_y = (fabsf(cy) > EPS) ? cy : 1.f;
    const float qxv = sgnf(cx) * rxy;
    const float qyv = sgnf(cy) * rxy;
    // |cx/safe_y| <= 1 when !xbig; |cy/safe_x| <= 1 when xbig (EPS-guarded
    // cases have tiny args) -> poly domain is valid on the taken branch.
    float bx = xbig ? qxv : qyv * FOUR_OVER_PI * atan_poly(cx / safe_y);
    float by = xbig ? qxv * FOUR_OVER_PI * atan_poly(cy / safe_x) : qyv;
    if (rc2 < EPS) { bx = 0.f; by = 0.f; }
    const float ux = fminf(fmaxf((bx + 1.f) * 0.5f * 3.f, 0.f), 3.f);
    const float uy = fminf(fmaxf((by + 1.f) * 0.5f * 3.f, 0.f), 3.f);
    const float uz = fminf(fmaxf((cz + 1.f) * 0.5f * 3.f, 0.f), 3.f);
    const int ix = imin(imax((int)floorf(ux), 0), 2);
    const int iy = imin(imax((int)floorf(uy), 0), 2);
    const int iz = imin(imax((int)floorf(uz), 0), 2);
    cellb = (iz * KK + iy) * KK + ix;
    ofx = ux - (float)ix; ofy = uy - (float)iy; ofz = uz - (float)iz;
}

// One launch, five independent prologue tasks, partitioned by blockIdx.
// geom first (heaviest), light tasks fill the dispatch tail.
__global__ __launch_bounds__(256) void prologue_kernel(
    const float* __restrict__ feats, const float* __restrict__ pos,
    const float* __restrict__ Wconv, const float* __restrict__ Wd,
    const float* __restrict__ bd,
    const int* __restrict__ eq, const int* __restrict__ en,
    const float* __restrict__ ev, int strideQ, int strideN,
    int* __restrict__ qstart, unsigned short* __restrict__ Wfrag,
    unsigned* __restrict__ fbp, float4* __restrict__ rec,
    float* __restrict__ out)
{
    const int bid = blockIdx.x;
    const int tid = threadIdx.x;
    if (bid < NB_G) {
        // ---- per-edge geometry record (valid edges only) ----
        const int e = bid * 256 + tid;
        if (ev[e] > 0.f) {
            const int q = eq[e * strideQ];
            const int n = en[e * strideN];
            int ib; float fx, fy, fz;
            edge_geom(pos, n, q, ib, fx, fy, fz);
            float4 r;
            r.x = fx; r.y = fy; r.z = fz;
            r.w = __int_as_float(n | (ib << 16) | (1 << 22));
            rec[e] = r;
        }
    } else if (bid < NB_G + NB_Q) {
        // ---- CSR offsets from sorted edge_q (padding keyed to N_PTS) ----
        const int e = (bid - NB_G) * 256 + tid;
        int k = (ev[e] > 0.f) ? eq[e * strideQ] : N_PTS;
        if (k > N_PTS) k = N_PTS;
        int kp = -1;
        if (e > 0) {
            kp = (ev[e - 1] > 0.f) ? eq[(e - 1) * strideQ] : N_PTS;
            if (kp > N_PTS) kp = N_PTS;
        }
        for (int q = kp + 1; q <= k; ++q) qstart[q] = e;
        if (e == E_PAD - 1)
            for (int q = k + 1; q <= N_PTS; ++q) qstart[q] = E_PAD;
    } else if (bid < NB_G + NB_Q + NB_W) {
        // ---- W -> bf16 B-fragment order: Wfrag[ks][nf][lane][j] ----
        const int idx = (bid - NB_G - NB_Q) * 256 + tid;
        const int j    = idx & 7;
        const int lane = (idx >> 3) & 63;
        const int nf   = (idx >> 9) & 3;
        const int ks   = idx >> 11;
        const int k    = ks * 32 + ((lane >> 4) << 3) + j;
        const int col  = nf * 16 + (lane & 15);
        Wfrag[idx] = f2bf(Wconv[k * COUT + col]);
    } else if (bid < NB_G + NB_Q + NB_W + NB_F) {
        // ---- feats f32 -> packed bf16 pairs: fbp[n*16+c] = (ch c, ch c+16)
        const int i = (bid - NB_G - NB_Q - NB_W) * 256 + tid;  // < 320000
        const int n = i >> 4, c = i & 15;
        fbp[i] = cvtpk(feats[n * CIN + c], feats[n * CIN + c + 16]);
    } else {
        // ---- dense head: out2 = feats @ Wd + bd, via MFMA ----
        const int db   = bid - NB_G - NB_Q - NB_W - NB_F;
        const int wv   = tid >> 6, lane = tid & 63;
        const int r16  = lane & 15, kgrp = lane >> 4;
        const int qb   = (db * 4 + wv) * 16;
        if (qb < N_PTS) {
            const float4 f0 = *(const float4*)(feats + (size_t)(qb + r16) * CIN + kgrp * 8);
            const float4 f1 = *(const float4*)(feats + (size_t)(qb + r16) * CIN + kgrp * 8 + 4);
            bf16x8 a8;
            ((unsigned*)&a8)[0] = cvtpk(f0.x, f0.y);
            ((unsigned*)&a8)[1] = cvtpk(f0.z, f0.w);
            ((unsigned*)&a8)[2] = cvtpk(f1.x, f1.y);
            ((unsigned*)&a8)[3] = cvtpk(f1.z, f1.w);
            #pragma unroll
            for (int nf = 0; nf < 4; ++nf) {
                bf16x8 b8;
                #pragma unroll
                for (int jp = 0; jp < 4; ++jp) {
                    const float w0 = Wd[(kgrp * 8 + jp * 2)     * COUT + nf * 16 + r16];
                    const float w1 = Wd[(kgrp * 8 + jp * 2 + 1) * COUT + nf * 16 + r16];
                    ((unsigned*)&b8)[jp] = cvtpk(w0, w1);
                }
                f32x4 acc = {0.f, 0.f, 0.f, 0.f};
                acc = __builtin_amdgcn_mfma_f32_16x16x32_bf16(a8, b8, acc, 0, 0, 0);
                const float bo = bd[nf * 16 + r16];
                #pragma unroll
                for (int rg = 0; rg < 4; ++rg) {
                    const int q = qb + kgrp * 4 + rg;
                    out[(size_t)N_PTS * COUT + q * COUT + nf * 16 + r16] = acc[rg] + bo;
                }
            }
        }
    }
}

// Fused (MT16, (512,4)): wave w owns ADJACENT queries {2w, 2w+1}; ONE
// masked chunk stream covers both (belongsA bit routes weights into
// bP_A/bP_B; dual accumulators; both flushed at end). Proven 34.7 shape.
__global__ __launch_bounds__(512, 4) void fused_kernel(
    const unsigned* __restrict__ fbp,
    const float4* __restrict__ rec,
    const unsigned short* __restrict__ Wfrag,
    const int* __restrict__ qstart, float* __restrict__ out)
{
    __shared__ __align__(16) unsigned short Zl[MT16 * KDIM];   // 64 KB
    __shared__ __align__(16) char scratch[9216];               // 9 KB union
    float4 (*ebuf)[2][36]   = (float4 (*)[2][36])scratch;          // phase A
    float  (*partial)[MT16][COUT] = (float (*)[MT16][COUT])scratch; // phase B+

    const int t    = threadIdx.x;
    const int w    = t >> 6;
    const int lane = t & 63;
    const int r16  = lane & 15;
    const int kgrp = lane >> 4;
    const int q0   = blockIdx.x * MT16;

    // ---------- Phase A: one masked chunk stream for 2 queries ----------
    const int dxc = r16 & 3, dyc = r16 >> 2;   // this lane's cell coords
    {
        const int lo  = qstart[q0 + 2 * w];
        const int mid = qstart[q0 + 2 * w + 1];
        const int hi  = qstart[q0 + 2 * w + 2];
        const int NC  = imax(1, (hi - lo + 31) >> 5);

        // initial stage: lanes<32 -> chunk 0, lanes>=32 -> chunk 1
        {
            const int sfi = lane >> 5, l32 = lane & 31;
            const int e   = lo + sfi * 32 + l32;
            float4 r;
            if (e < hi) r = rec[e];
            else { r.x = 0.f; r.y = 0.f; r.z = 0.f; r.w = __int_as_float(0); }
            int meta = __float_as_int(r.w);
            if (e < mid) meta |= (1 << 23);      // belongsA
            r.w = __int_as_float(meta);
            ebuf[w][sfi][l32 + (l32 >> 3)] = r;  // padded index
        }

        f32x4 accA[2][4], accB[2][4];
        #pragma unroll
        for (int mf = 0; mf < 2; ++mf)
            #pragma unroll
            for (int nf = 0; nf < 4; ++nf) {
                accA[mf][nf] = (f32x4){0.f, 0.f, 0.f, 0.f};
                accB[mf][nf] = (f32x4){0.f, 0.f, 0.f, 0.f};
            }

        for (int fi = 0; fi < NC; ++fi) {
            const float4* buf = &ebuf[w][fi & 1][0];
            bf16x8 bPA[4], bPB[4], af[2];
            #pragma unroll
            for (int jp = 0; jp < 4; ++jp) {
                float pA[2][4], pB[2][4];
                #pragma unroll
                for (int h = 0; h < 2; ++h) {
                    const int j = jp * 2 + h;
                    const float4 r = buf[kgrp * 9 + j];   // padded index
                    const int meta = __float_as_int(r.w);
                    const int n    = meta & 0xFFFF;
                    const int ib   = (meta >> 16) & 63;
                    const float valid = (meta & (1 << 22)) ? 1.f : 0.f;
                    const float selA  = (meta & (1 << 23)) ? 1.f : 0.f;
                    const int ix = ib & 3, iy = (ib >> 2) & 3, iz = ib >> 4;
                    const float wx = (dxc == ix) ? (1.f - r.x)
                                   : ((dxc == ix + 1) ? r.x : 0.f);
                    const float wy = (dyc == iy) ? (1.f - r.y)
                                   : ((dyc == iy + 1) ? r.y : 0.f);
                    const float wxy = wx * wy * valid;
                    const float z0 = wxy * (1.f - r.z), z1 = wxy * r.z;
                    float p0 = (iz == 0) ? z0 : 0.f;
                    float p1 = (iz == 0) ? z1 : ((iz == 1) ? z0 : 0.f);
                    float p2 = (iz == 2) ? z0 : ((iz == 1) ? z1 : 0.f);
                    float p3 = (iz == 2) ? z1 : 0.f;
                    pA[h][0] = p0 * selA;  pB[h][0] = p0 - pA[h][0];
                    pA[h][1] = p1 * selA;  pB[h][1] = p1 - pA[h][1];
                    pA[h][2] = p2 * selA;  pB[h][2] = p2 - pA[h][2];
                    pA[h][3] = p3 * selA;  pB[h][3] = p3 - pA[h][3];
                    // packed gather: one 4B load = channels r16 and r16+16
                    const unsigned uf = fbp[(size_t)n * 16 + r16];
                    af[0][j] = (short)(uf & 0xFFFFu);
                    af[1][j] = (short)(uf >> 16);
                }
                #pragma unroll
                for (int nf = 0; nf < 4; ++nf) {
                    ((unsigned*)&bPA[nf])[jp] = cvtpk(pA[0][nf], pA[1][nf]);
                    ((unsigned*)&bPB[nf])[jp] = cvtpk(pB[0][nf], pB[1][nf]);
                }
            }
            #pragma unroll
            for (int nf = 0; nf < 4; ++nf) {
                accA[0][nf] = __builtin_amdgcn_mfma_f32_16x16x32_bf16(
                    af[0], bPA[nf], accA[0][nf], 0, 0, 0);
                accA[1][nf] = __builtin_amdgcn_mfma_f32_16x16x32_bf16(
                    af[1], bPA[nf], accA[1][nf], 0, 0, 0);
                accB[0][nf] = __builtin_amdgcn_mfma_f32_16x16x32_bf16(
                    af[0], bPB[nf], accB[0][nf], 0, 0, 0);
                accB[1][nf] = __builtin_amdgcn_mfma_f32_16x16x32_bf16(
                    af[1], bPB[nf], accB[1][nf], 0, 0, 0);
            }
            // stage chunk fi+2 into the buffer just consumed (lanes<32)
            const int nfi = fi + 2;
            if (nfi < NC && lane < 32) {
                const int e = lo + nfi * 32 + lane;
                float4 r;
                if (e < hi) r = rec[e];
                else { r.x = 0.f; r.y = 0.f; r.z = 0.f;
                       r.w = __int_as_float(0); }
                int meta = __float_as_int(r.w);
                if (e < mid) meta |= (1 << 23);
                r.w = __int_as_float(meta);
                ebuf[w][fi & 1][lane + (lane >> 3)] = r;
            }
        }
        // flush both queries' Z rows (qsA = 2w, qsB = 2w+1)
        #pragma unroll
        for (int half = 0; half < 2; ++half) {
            const int qs = 2 * w + half;
            #pragma unroll
            for (int mf = 0; mf < 2; ++mf)
                #pragma unroll
                for (int nf = 0; nf < 4; ++nf) {
                    const f32x4 a = half ? accB[mf][nf] : accA[mf][nf];
                    uint2 dv;
                    dv.x = cvtpk(a[0], a[1]);
                    dv.y = cvtpk(a[2], a[3]);
                    const int g      = nf * 16 + r16;
                    const int slot   = g * 64 + qs * 4 + mf * 2 + (kgrp >> 1);
                    const int stored = slot ^ (g & 7);
                    *(uint2*)&Zl[stored * 8 + (kgrp & 1) * 4] = dv;
                }
        }
    }
    __syncthreads();

    // ---------- Phase B: out = Zl x Wfrag (dual accumulator) ----------
    {
        const int kw  = w >> 2;      // K-half
        const int nfB = w & 3;       // col-frag
        f32x4 acc0 = {0.f, 0.f, 0.f, 0.f};
        f32x4 acc1 = {0.f, 0.f, 0.f, 0.f};
        __builtin_amdgcn_s_setprio(1);
        #pragma unroll 4
        for (int i = 0; i < 16; ++i) {
            const int ksA = kw * 32 + 2 * i;
            const int ksB = ksA + 1;
            const int stA = (ksA * 64 + r16 * 4 + kgrp) ^ (ksA & 7);
            const int stB = (ksB * 64 + r16 * 4 + kgrp) ^ (ksB & 7);
            const bf16x8 aA = *(const bf16x8*)&Zl[stA * 8];
            const bf16x8 aB = *(const bf16x8*)&Zl[stB * 8];
            const bf16x8 bA =
                *(const bf16x8*)(Wfrag + (((ksA * 4 + nfB) * 64) + lane) * 8);
            const bf16x8 bB =
                *(const bf16x8*)(Wfrag + (((ksB * 4 + nfB) * 64) + lane) * 8);
            acc0 = __builtin_amdgcn_mfma_f32_16x16x32_bf16(aA, bA, acc0, 0, 0, 0);
            acc1 = __builtin_amdgcn_mfma_f32_16x16x32_bf16(aB, bB, acc1, 0, 0, 0);
        }
        __builtin_amdgcn_s_setprio(0);
        const f32x4 accB = acc0 + acc1;
        #pragma unroll
        for (int rg = 0; rg < 4; ++rg)
            partial[kw][kgrp * 4 + rg][nfB * 16 + r16] = accB[rg];
    }
    __syncthreads();

    // ---------- Epilogue: reduce K-halves (conv output only) ----------
    #pragma unroll
    for (int rep = 0; rep < MT16 * COUT / 512; ++rep) {
        const int idx = rep * 512 + t;
        const int r = idx >> 6, o = idx & 63;
        out[(q0 + r) * COUT + o] = partial[0][r][o] + partial[1][r][o];
    }
}

// ---------------- Fallback (round-2 monolithic) if ws too small ----------
__global__ __launch_bounds__(256) void conv_dense_kernel(
    const float* __restrict__ feats, const float* __restrict__ pos,
    const float* __restrict__ Wconv, const float* __restrict__ Wd,
    const float* __restrict__ bd,
    const int* __restrict__ en, const float* __restrict__ ev,
    const int* __restrict__ qstart, int strideN,
    float* __restrict__ out)
{
    __shared__ float Z[QB][KF][CIN];
    __shared__ float partial[4][QB][COUT];
    __shared__ int   rec_n[256], rec_b[256];
    __shared__ float rec_fx[256], rec_fy[256], rec_fz[256];
    __shared__ int   qs9[QB + 1];

    const int t = threadIdx.x, wave = t >> 6, lane = t & 63;
    const int q0 = blockIdx.x * QB;
    if (t <= QB) qs9[t] = qstart[q0 + t];
    float* zf = &Z[0][0][0];
    for (int j = t; j < QB * KF * CIN; j += 256) zf[j] = 0.f;
    __syncthreads();
    const int eLo = qs9[0], eHi = qs9[QB];
    const int ci = lane & 31, dbase = lane >> 5;
    for (int cb = eLo; cb < eHi; cb += 256) {
        const int cnt = imin(256, eHi - cb);
        if (t < cnt) {
            const int e = cb + t;
            int q = q0;
            #pragma unroll
            for (int s = 1; s < QB; ++s) if (e >= qs9[s]) q = q0 + s;
            int nn = ((const int*)en)[e];
            int ib; float fx, fy, fz;
            edge_geom(pos, nn, q, ib, fx, fy, fz);
            rec_n[t] = nn; rec_b[t] = ib;
            rec_fx[t] = fx; rec_fy[t] = fy; rec_fz[t] = fz;
        }
        __syncthreads();
        for (int s = 0; s < QB / 4; ++s) {
            const int qs = wave * (QB / 4) + s;
            const int lo = imax(qs9[qs], cb);
            const int hi = imin(qs9[qs + 1], cb + cnt);
            for (int e = lo; e < hi; ++e) {
                const int r = e - cb;
                const int n = rec_n[r], ib = rec_b[r];
                const float fx = rec_fx[r], fy = rec_fy[r], fz = rec_fz[r];
                const float fj = feats[n * CIN + ci];
                const float wxf = dbase ? fx : 1.f - fx;
                #pragma unroll
                for (int dd = 0; dd < 4; ++dd) {
                    const int dy = dd & 1, dz = dd >> 1;
                    const float wv = (dz ? fz : 1.f - fz) * (dy ? fy : 1.f - fy) * wxf;
                    Z[qs][ib + dz * 16 + dy * 4 + dbase][ci] += fj * wv;
                }
            }
        }
        __syncthreads();
    }
    float acc[QB];
    #pragma unroll
    for (int qs = 0; qs < QB; ++qs) acc[qs] = 0.f;
    const int o = lane;
    for (int kk = 0; kk < KF / 4; ++kk) {
        const int kf = wave * (KF / 4) + kk;
        #pragma unroll
        for (int ii = 0; ii < CIN; ii += 4) {
            float4 z4[QB];
            #pragma unroll
            for (int qs = 0; qs < QB; ++qs)
                z4[qs] = *(const float4*)&Z[qs][kf][ii];
            #pragma unroll
            for (int c = 0; c < 4; ++c) {
                const float wv = Wconv[(kf * CIN + ii + c) * COUT + o];
                #pragma unroll
                for (int qs = 0; qs < QB; ++qs)
                    acc[qs] += wv * ((const float*)&z4[qs])[c];
            }
        }
    }
    #pragma unroll
    for (int qs = 0; qs < QB; ++qs) partial[wave][qs][o] = acc[qs];
    __syncthreads();
    for (int s = 0; s < QB / 4; ++s) {
        const int qs = wave * (QB / 4) + s;
        const int q  = q0 + qs;
        out[q * COUT + o] = partial[0][qs][o] + partial[1][qs][o] +
                            partial[2][qs][o] + partial[3][qs][o];
        float dacc = bd[o];
        #pragma unroll
        for (int ii = 0; ii < CIN; ++ii)
            dacc += feats[q * CIN + ii] * Wd[ii * COUT + o];
        out[N_PTS * COUT + q * COUT + o] = dacc;
    }
}

// Repack en to int32 contiguous (fallback path only).
__global__ __launch_bounds__(256) void pack_en_kernel(
    const int* __restrict__ en, int stride, int* __restrict__ en32)
{
    const int e = blockIdx.x * 256 + threadIdx.x;
    if (e < E_PAD) en32[e] = en[e * stride];
}

// qstart-only builder for the fallback path.
__global__ __launch_bounds__(256) void build_qstart_kernel(
    const int* __restrict__ eq, const float* __restrict__ ev,
    int stride, int* __restrict__ qstart)
{
    int e = blockIdx.x * 256 + threadIdx.x;
    if (e >= E_PAD) return;
    int k = (ev[e] > 0.f) ? eq[e * stride] : N_PTS;
    if (k > N_PTS) k = N_PTS;
    int kp = -1;
    if (e > 0) {
        kp = (ev[e - 1] > 0.f) ? eq[(e - 1) * stride] : N_PTS;
        if (kp > N_PTS) kp = N_PTS;
    }
    for (int q = kp + 1; q <= k; ++q) qstart[q] = e;
    if (e == E_PAD - 1) {
        for (int q = k + 1; q <= N_PTS; ++q) qstart[q] = E_PAD;
    }
}

extern "C" void kernel_launch(void* const* d_in, const int* in_sizes, int n_in,
                              void* d_out, int out_size, void* d_ws, size_t ws_size,
                              hipStream_t stream)
{
    const float* feats = (const float*)d_in[0];
    const float* pos   = (const float*)d_in[1];
    const float* Wconv = (const float*)d_in[2];
    const float* Wd    = (const float*)d_in[3];
    const float* bd    = (const float*)d_in[4];
    const int*   eq    = (const int*)d_in[5];
    const int*   en    = (const int*)d_in[6];
    const float* ev    = (const float*)d_in[7];
    const int strideQ = in_sizes[5] / E_PAD;   // int32 vs int64 hedge
    const int strideN = in_sizes[6] / E_PAD;

    int* qstart = (int*)d_ws;
    const size_t offW  = 81920;                       // Wfrag   (256 KB)
    const size_t offFB = offW + 262144;               // fbp     (1.28 MB)
    const size_t offR  = offFB + (size_t)N_PTS * CIN * 2;  // rec (4 MB)
    const size_t needed = offR + (size_t)E_PAD * 16;

    if (ws_size >= needed) {
        unsigned short* Wfrag = (unsigned short*)((char*)d_ws + offW);
        unsigned*       fbp   = (unsigned*)((char*)d_ws + offFB);
        float4*         rec   = (float4*)((char*)d_ws + offR);
        prologue_kernel<<<NB_G + NB_Q + NB_W + NB_F + NB_D, 256, 0, stream>>>(
            feats, pos, Wconv, Wd, bd, eq, en, ev, strideQ, strideN,
            qstart, Wfrag, fbp, rec, (float*)d_out);
        fused_kernel<<<N_PTS / MT16, 512, 0, stream>>>(
            fbp, rec, Wfrag, qstart, (float*)d_out);
    } else {
        build_qstart_kernel<<<E_PAD / 256, 256, 0, stream>>>(
            eq, ev, strideQ, qstart);
        int* en32 = (int*)((char*)d_ws + offW);
        pack_en_kernel<<<E_PAD / 256, 256, 0, stream>>>(en, strideN, en32);
        conv_dense_kernel<<<N_PTS / QB, 256, 0, stream>>>(
            feats, pos, Wconv, Wd, bd, en32, ev, qstart, 1, (float*)d_out);
    }
}